// Round 1
// baseline (451.526 us; speedup 1.0000x reference)
//
#include <hip/hip_runtime.h>
#include <hip/hip_bf16.h>
#include <stdint.h>

// Problem constants
#define SEQ  2048
#define DIMM 1024
#define NH   16
#define DH   64
#define NB   4
#define MROWS (NB*SEQ)   // 8192

typedef __attribute__((ext_vector_type(8))) short bf16x8;
typedef __attribute__((ext_vector_type(4))) float f32x4;

__device__ __forceinline__ unsigned short f2bf(float f) {
    union { float f; uint32_t u; } c; c.f = f;
    uint32_t r = c.u + 0x7fff + ((c.u >> 16) & 1);
    return (unsigned short)(r >> 16);
}

__device__ __forceinline__ void gload_lds16(const void* g, void* lds) {
    __builtin_amdgcn_global_load_lds(
        (const __attribute__((address_space(1))) unsigned int*)(g),
        (__attribute__((address_space(3))) unsigned int*)(lds),
        16, 0, 0);
}

// ---------------- fp32 -> bf16 elementwise convert (vectorized) -------------
__global__ __launch_bounds__(256) void k_conv_bf16(const float* __restrict__ in,
                                                   unsigned short* __restrict__ out,
                                                   int n4) {
    int i = blockIdx.x * 256 + threadIdx.x;
    if (i >= n4) return;
    float4 v = ((const float4*)in)[i];
    ushort4 o;
    o.x = f2bf(v.x); o.y = f2bf(v.y); o.z = f2bf(v.z); o.w = f2bf(v.w);
    ((ushort4*)out)[i] = o;
}

// ------------- W [K][N] fp32  ->  Wt [N][K] bf16 (tiled transpose) ----------
__global__ __launch_bounds__(256) void k_transpose(const float* __restrict__ W,
                                                   unsigned short* __restrict__ Wt,
                                                   int K, int N) {
    __shared__ unsigned short tile[32][33];
    int tn = blockIdx.x, tk = blockIdx.y;
    int lx = threadIdx.x & 31, ly = threadIdx.x >> 5;  // 32 x 8
    #pragma unroll
    for (int i = 0; i < 32; i += 8) {
        int k = tk * 32 + ly + i;
        int n = tn * 32 + lx;
        tile[ly + i][lx] = f2bf(W[(size_t)k * N + n]);
    }
    __syncthreads();
    int k2 = tk * 32 + lx;
    #pragma unroll
    for (int i = 0; i < 32; i += 8) {
        int n2 = tn * 32 + ly + i;
        Wt[(size_t)n2 * K + k2] = tile[lx][ly + i];
    }
}

// --------- C[M][N] = A[M][K] * Bt[N][K]^T   (bf16 in, fp32/bf16 out) --------
// m97-style: 128x128 tile, BK=32, 4 waves (2x2), 4x4 16x16x32 MFMA frags/wave.
template<int OUT_BF16>
__global__ __launch_bounds__(256) void k_gemm_bt(const unsigned short* __restrict__ A,
                                                 const unsigned short* __restrict__ Bt,
                                                 void* __restrict__ Cv,
                                                 int M, int N_, int K) {
    constexpr int BM = 128, BN = 128, BK = 32;
    __shared__ unsigned short lA[BM * BK];
    __shared__ unsigned short lB[BN * BK];
    const int ntile = N_ / BN;
    const int tm = blockIdx.x / ntile;
    const int tn = blockIdx.x % ntile;
    const int t = threadIdx.x;
    const int w = t >> 6, l = t & 63;
    const int wr = w >> 1, wc = w & 1;

    const unsigned short* Abase = A + (size_t)tm * BM * K;
    const unsigned short* Bbase = Bt + (size_t)tn * BN * K;

    f32x4 acc[4][4] = {};

    for (int k0 = 0; k0 < K; k0 += BK) {
        __syncthreads();  // protect LDS from previous iteration's readers
        #pragma unroll
        for (int i = 0; i < 2; ++i) {
            int offL = (i * 4 + w) * 1024 + l * 16;  // byte offset in 8KB tile
            int row = offL >> 6;                     // 64B per row (32 bf16)
            int kb  = offL & 63;
            gload_lds16((const char*)(Abase + (size_t)row * K + k0) + kb,
                        (char*)lA + (i * 4 + w) * 1024);
            gload_lds16((const char*)(Bbase + (size_t)row * K + k0) + kb,
                        (char*)lB + (i * 4 + w) * 1024);
        }
        __syncthreads();

        bf16x8 af[4], bfv[4];
        #pragma unroll
        for (int i = 0; i < 4; ++i)
            af[i] = *(const bf16x8*)&lA[(wr * 64 + i * 16 + (l & 15)) * BK + (l >> 4) * 8];
        #pragma unroll
        for (int j = 0; j < 4; ++j)
            bfv[j] = *(const bf16x8*)&lB[(wc * 64 + j * 16 + (l & 15)) * BK + (l >> 4) * 8];
        #pragma unroll
        for (int i = 0; i < 4; ++i)
            #pragma unroll
            for (int j = 0; j < 4; ++j)
                acc[i][j] = __builtin_amdgcn_mfma_f32_16x16x32_bf16(af[i], bfv[j], acc[i][j], 0, 0, 0);
    }

    // epilogue: C row = (lane>>4)*4 + r, col = lane&15  (m89-verified layout)
    float* Cf = (float*)Cv;
    unsigned short* Cb = (unsigned short*)Cv;
    const int row0 = tm * BM + wr * 64 + (l >> 4) * 4;
    const int col0 = tn * BN + wc * 64 + (l & 15);
    #pragma unroll
    for (int i = 0; i < 4; ++i)
        #pragma unroll
        for (int j = 0; j < 4; ++j)
            #pragma unroll
            for (int r = 0; r < 4; ++r) {
                size_t idx = (size_t)(row0 + i * 16 + r) * N_ + (col0 + j * 16);
                if (OUT_BF16) Cb[idx] = f2bf(acc[i][j][r]);
                else          Cf[idx] = acc[i][j][r];
            }
}

// ----------------------- causal flash attention -----------------------------
// qkv: [8192][3072] bf16 (q | k | v each 1024 cols, head h at h*64)
// out: [8192][1024] bf16  (b, n, h*64+dh)
// 1 block = (b, h, q-tile of 64). 4 waves x 16 q rows. KV tiles of 64.
__global__ __launch_bounds__(256) void k_attn(const unsigned short* __restrict__ qkv,
                                              unsigned short* __restrict__ out) {
    const int bid = blockIdx.x;
    const int qt = bid & 31;
    const int h  = (bid >> 5) & 15;
    const int b  = bid >> 9;
    const int t = threadIdx.x, w = t >> 6, l = t & 63;

    __shared__ unsigned short VT[64 * 72];      // V^T tile [dh][kv], pad 72
    __shared__ unsigned short Pl[4][16 * 72];   // per-wave P [q][kv], pad 72

    const unsigned short* qp = qkv + (size_t)(b * SEQ) * 3072 + h * 64;
    const unsigned short* kp = qp + 1024;
    const unsigned short* vp = qp + 2048;

    const int q0 = qt * 64 + w * 16;            // wave's first q row in seq
    const int lr = l & 15, lc = l >> 4;

    // Q fragments, hoisted (A-operand: row = lane&15, k = (lane>>4)*8)
    bf16x8 qf[2];
    #pragma unroll
    for (int c = 0; c < 2; ++c)
        qf[c] = *(const bf16x8*)(qp + (size_t)(q0 + lr) * 3072 + c * 32 + lc * 8);

    f32x4 accO[4] = {};                          // O: 4 dh-frags of 16x16
    float m_run[4], l_run[4];
    #pragma unroll
    for (int r = 0; r < 4; ++r) { m_run[r] = -INFINITY; l_run[r] = 0.f; }

    for (int kt = 0; kt <= qt; ++kt) {
        const int kv0 = kt * 64;
        __syncthreads();
        // stage V^T: [64 kv][64 dh] global -> [dh][kv] LDS
        #pragma unroll
        for (int i = 0; i < 2; ++i) {
            int c = t + 256 * i;                 // chunk id 0..511
            int kv = c >> 3, d0 = (c & 7) * 8;
            bf16x8 v = *(const bf16x8*)(vp + (size_t)(kv0 + kv) * 3072 + d0);
            #pragma unroll
            for (int e = 0; e < 8; ++e)
                VT[(d0 + e) * 72 + kv] = ((unsigned short*)&v)[e];
        }
        __syncthreads();

        // QK^T: S frags, B-operand K loaded direct from global (L2-resident)
        f32x4 s[4] = {};
        #pragma unroll
        for (int j = 0; j < 4; ++j)
            #pragma unroll
            for (int c = 0; c < 2; ++c) {
                bf16x8 kf = *(const bf16x8*)(kp + (size_t)(kv0 + j * 16 + lr) * 3072 + c * 32 + lc * 8);
                s[j] = __builtin_amdgcn_mfma_f32_16x16x32_bf16(qf[c], kf, s[j], 0, 0, 0);
            }

        const bool boundary = (kt == qt);
        // online softmax per q-row r (row = lc*4 + r, col = j*16 + lr)
        #pragma unroll
        for (int r = 0; r < 4; ++r) {
            float mr = -1e30f;
            #pragma unroll
            for (int j = 0; j < 4; ++j) {
                float v = s[j][r] * 0.125f;
                if (boundary && (kv0 + j * 16 + lr) > (q0 + lc * 4 + r)) v = -1e30f;
                s[j][r] = v;
                mr = fmaxf(mr, v);
            }
            #pragma unroll
            for (int d = 1; d < 16; d <<= 1) mr = fmaxf(mr, __shfl_xor(mr, d));
            float mnew = fmaxf(m_run[r], mr);
            float fct  = __expf(m_run[r] - mnew);
            float ps = 0.f;
            #pragma unroll
            for (int j = 0; j < 4; ++j) {
                float p = __expf(s[j][r] - mnew);
                s[j][r] = p;
                ps += p;
            }
            #pragma unroll
            for (int d = 1; d < 16; d <<= 1) ps += __shfl_xor(ps, d);
            l_run[r] = l_run[r] * fct + ps;
            m_run[r] = mnew;
            #pragma unroll
            for (int f = 0; f < 4; ++f) accO[f][r] *= fct;
        }

        // P -> wave-private LDS (transpose to A-operand layout), then PV
        #pragma unroll
        for (int r = 0; r < 4; ++r)
            #pragma unroll
            for (int j = 0; j < 4; ++j)
                Pl[w][(lc * 4 + r) * 72 + j * 16 + lr] = f2bf(s[j][r]);

        bf16x8 pa[2];
        #pragma unroll
        for (int c = 0; c < 2; ++c)
            pa[c] = *(const bf16x8*)&Pl[w][lr * 72 + c * 32 + lc * 8];
        #pragma unroll
        for (int f = 0; f < 4; ++f)
            #pragma unroll
            for (int c = 0; c < 2; ++c) {
                bf16x8 vf = *(const bf16x8*)&VT[(f * 16 + lr) * 72 + c * 32 + lc * 8];
                accO[f] = __builtin_amdgcn_mfma_f32_16x16x32_bf16(pa[c], vf, accO[f], 0, 0, 0);
            }
    }

    // epilogue: O /= l_run, write bf16
    unsigned short* op = out + (size_t)(b * SEQ) * DIMM + h * 64;
    #pragma unroll
    for (int r = 0; r < 4; ++r) {
        float inv = 1.0f / l_run[r];
        #pragma unroll
        for (int f = 0; f < 4; ++f)
            op[(size_t)(q0 + lc * 4 + r) * DIMM + f * 16 + lr] = f2bf(accO[f][r] * inv);
    }
}

// ---------------------------------------------------------------------------
extern "C" void kernel_launch(void* const* d_in, const int* in_sizes, int n_in,
                              void* d_out, int out_size, void* d_ws, size_t ws_size,
                              hipStream_t stream) {
    const float* x     = (const float*)d_in[0];   // [4,2048,1024]
    const float* w_qkv = (const float*)d_in[1];   // [1024,3072]
    const float* w_out = (const float*)d_in[2];   // [1024,1024]

    unsigned short* x_bf   = (unsigned short*)d_ws;                  // 8192*1024
    unsigned short* wqkvT  = x_bf   + (size_t)MROWS * DIMM;          // 3072*1024
    unsigned short* woutT  = wqkvT  + (size_t)3 * DIMM * DIMM;       // 1024*1024
    unsigned short* qkv_bf = woutT  + (size_t)DIMM * DIMM;           // 8192*3072
    unsigned short* aout   = qkv_bf + (size_t)MROWS * 3 * DIMM;      // 8192*1024

    // 1. converts / transposes
    k_conv_bf16<<<(MROWS * DIMM / 4 + 255) / 256, 256, 0, stream>>>(x, x_bf, MROWS * DIMM / 4);
    dim3 g1(3 * DIMM / 32, DIMM / 32);
    k_transpose<<<g1, 256, 0, stream>>>(w_qkv, wqkvT, DIMM, 3 * DIMM);
    dim3 g2(DIMM / 32, DIMM / 32);
    k_transpose<<<g2, 256, 0, stream>>>(w_out, woutT, DIMM, DIMM);

    // 2. QKV projection: [8192,1024] x [1024,3072] -> bf16 [8192,3072]
    k_gemm_bt<1><<<(MROWS / 128) * (3 * DIMM / 128), 256, 0, stream>>>(
        x_bf, wqkvT, qkv_bf, MROWS, 3 * DIMM, DIMM);

    // 3. causal flash attention -> bf16 [8192,1024]
    k_attn<<<NB * NH * (SEQ / 64), 256, 0, stream>>>(qkv_bf, aout);

    // 4. output projection: [8192,1024] x [1024,1024] -> fp32 d_out
    k_gemm_bt<0><<<(MROWS / 128) * (DIMM / 128), 256, 0, stream>>>(
        aout, woutT, d_out, MROWS, DIMM, DIMM);
}

// Round 2
// 399.959 us; speedup vs baseline: 1.1289x; 1.1289x over previous
//
#include <hip/hip_runtime.h>
#include <hip/hip_bf16.h>
#include <stdint.h>

// Problem constants
#define SEQ  2048
#define DIMM 1024
#define NH   16
#define DH   64
#define NB   4
#define MROWS (NB*SEQ)   // 8192

typedef __attribute__((ext_vector_type(8))) short bf16x8;
typedef __attribute__((ext_vector_type(4))) float f32x4;

__device__ __forceinline__ unsigned short f2bf(float f) {
    union { float f; uint32_t u; } c; c.f = f;
    uint32_t r = c.u + 0x7fff + ((c.u >> 16) & 1);
    return (unsigned short)(r >> 16);
}

__device__ __forceinline__ void gload_lds16(const void* g, void* lds) {
    __builtin_amdgcn_global_load_lds(
        (const __attribute__((address_space(1))) unsigned int*)(g),
        (__attribute__((address_space(3))) unsigned int*)(lds),
        16, 0, 0);
}

// ---------------- fp32 -> bf16 elementwise convert (vectorized) -------------
__global__ __launch_bounds__(256) void k_conv_bf16(const float* __restrict__ in,
                                                   unsigned short* __restrict__ out,
                                                   int n4) {
    int i = blockIdx.x * 256 + threadIdx.x;
    if (i >= n4) return;
    float4 v = ((const float4*)in)[i];
    ushort4 o;
    o.x = f2bf(v.x); o.y = f2bf(v.y); o.z = f2bf(v.z); o.w = f2bf(v.w);
    ((ushort4*)out)[i] = o;
}

// ------------- W [K][N] fp32  ->  Wt [N][K] bf16 (tiled transpose) ----------
__global__ __launch_bounds__(256) void k_transpose(const float* __restrict__ W,
                                                   unsigned short* __restrict__ Wt,
                                                   int K, int N) {
    __shared__ unsigned short tile[32][33];
    int tn = blockIdx.x, tk = blockIdx.y;
    int lx = threadIdx.x & 31, ly = threadIdx.x >> 5;  // 32 x 8
    #pragma unroll
    for (int i = 0; i < 32; i += 8) {
        int k = tk * 32 + ly + i;
        int n = tn * 32 + lx;
        tile[ly + i][lx] = f2bf(W[(size_t)k * N + n]);
    }
    __syncthreads();
    int k2 = tk * 32 + lx;
    #pragma unroll
    for (int i = 0; i < 32; i += 8) {
        int n2 = tn * 32 + ly + i;
        Wt[(size_t)n2 * K + k2] = tile[lx][ly + i];
    }
}

// ---- V columns of qkv  ->  vt[bh][d=64][n=2048] bf16 (per-head V^T) --------
__global__ __launch_bounds__(256) void k_transpose_v(const unsigned short* __restrict__ qkv,
                                                     unsigned short* __restrict__ vt) {
    __shared__ unsigned short tile[64 * 72];
    const int nt = blockIdx.x & 31;      // kv tile of 64
    const int bh = blockIdx.x >> 5;      // 0..63
    const int b = bh >> 4, h = bh & 15;
    const int n0 = nt * 64;
    const int t = threadIdx.x;

    // read V rows (coalesced 16B), stage to LDS [kv][72-padded d]
    #pragma unroll
    for (int i = 0; i < 2; ++i) {
        int c = t + 256 * i;             // 0..511
        int kv = c >> 3, d0 = (c & 7) * 8;
        bf16x8 v = *(const bf16x8*)(qkv + (size_t)(b * SEQ + n0 + kv) * 3072 + 2048 + h * 64 + d0);
        *(bf16x8*)&tile[kv * 72 + d0] = v;
    }
    __syncthreads();
    // write V^T rows (coalesced 16B)
    #pragma unroll
    for (int i = 0; i < 2; ++i) {
        int c = t + 256 * i;
        int d = c >> 3, k0 = (c & 7) * 8;
        bf16x8 o;
        #pragma unroll
        for (int e = 0; e < 8; ++e)
            ((unsigned short*)&o)[e] = tile[(k0 + e) * 72 + d];
        *(bf16x8*)(vt + (size_t)(bh * 64 + d) * SEQ + n0 + k0) = o;
    }
}

// --------- C[M][N] = A[M][K] * Bt[N][K]^T   (bf16 in, fp32/bf16 out) --------
template<int OUT_BF16>
__global__ __launch_bounds__(256) void k_gemm_bt(const unsigned short* __restrict__ A,
                                                 const unsigned short* __restrict__ Bt,
                                                 void* __restrict__ Cv,
                                                 int M, int N_, int K) {
    constexpr int BM = 128, BN = 128, BK = 32;
    __shared__ unsigned short lA[BM * BK];
    __shared__ unsigned short lB[BN * BK];
    const int ntile = N_ / BN;
    const int tm = blockIdx.x / ntile;
    const int tn = blockIdx.x % ntile;
    const int t = threadIdx.x;
    const int w = t >> 6, l = t & 63;
    const int wr = w >> 1, wc = w & 1;

    const unsigned short* Abase = A + (size_t)tm * BM * K;
    const unsigned short* Bbase = Bt + (size_t)tn * BN * K;

    f32x4 acc[4][4] = {};

    for (int k0 = 0; k0 < K; k0 += BK) {
        __syncthreads();
        #pragma unroll
        for (int i = 0; i < 2; ++i) {
            int offL = (i * 4 + w) * 1024 + l * 16;
            int row = offL >> 6;
            int kb  = offL & 63;
            gload_lds16((const char*)(Abase + (size_t)row * K + k0) + kb,
                        (char*)lA + (i * 4 + w) * 1024);
            gload_lds16((const char*)(Bbase + (size_t)row * K + k0) + kb,
                        (char*)lB + (i * 4 + w) * 1024);
        }
        __syncthreads();

        bf16x8 af[4], bfv[4];
        #pragma unroll
        for (int i = 0; i < 4; ++i)
            af[i] = *(const bf16x8*)&lA[(wr * 64 + i * 16 + (l & 15)) * BK + (l >> 4) * 8];
        #pragma unroll
        for (int j = 0; j < 4; ++j)
            bfv[j] = *(const bf16x8*)&lB[(wc * 64 + j * 16 + (l & 15)) * BK + (l >> 4) * 8];
        #pragma unroll
        for (int i = 0; i < 4; ++i)
            #pragma unroll
            for (int j = 0; j < 4; ++j)
                acc[i][j] = __builtin_amdgcn_mfma_f32_16x16x32_bf16(af[i], bfv[j], acc[i][j], 0, 0, 0);
    }

    float* Cf = (float*)Cv;
    unsigned short* Cb = (unsigned short*)Cv;
    const int row0 = tm * BM + wr * 64 + (l >> 4) * 4;
    const int col0 = tn * BN + wc * 64 + (l & 15);
    #pragma unroll
    for (int i = 0; i < 4; ++i)
        #pragma unroll
        for (int j = 0; j < 4; ++j)
            #pragma unroll
            for (int r = 0; r < 4; ++r) {
                size_t idx = (size_t)(row0 + i * 16 + r) * N_ + (col0 + j * 16);
                if (OUT_BF16) Cb[idx] = f2bf(acc[i][j][r]);
                else          Cf[idx] = acc[i][j][r];
            }
}

// ----------------------- causal flash attention (v2) ------------------------
// Barrier-free: K and pre-transposed V^T read direct from global (L2-resident).
// One block = (b, h, q-tile pair {i, 31-i}) -> uniform 33 tile-units of work;
// K/V fragment loads shared between the two q-tiles.
__global__ __launch_bounds__(256) void k_attn2(const unsigned short* __restrict__ qkv,
                                               const unsigned short* __restrict__ vt,
                                               unsigned short* __restrict__ out) {
    // bijective XCD swizzle: nwg=1024, 128 per XCD
    const int wid = (blockIdx.x & 7) * 128 + (blockIdx.x >> 3);
    const int bh = wid >> 4;            // 0..63
    const int pair = wid & 15;          // 0..15
    const int b = bh >> 4, h = bh & 15;
    const int qtA = pair, qtB = 31 - pair;
    const int t = threadIdx.x, w = t >> 6, l = t & 63;
    const int lr = l & 15, lc = l >> 4;

    __shared__ unsigned short Pl[4][2][16 * 72];   // per-wave P [q][kv]

    const unsigned short* qp = qkv + (size_t)(b * SEQ) * 3072 + h * 64;
    const unsigned short* kp = qp + 1024;
    const unsigned short* vb = vt + (size_t)bh * 64 * SEQ;

    const int q0A = qtA * 64 + w * 16;
    const int q0B = qtB * 64 + w * 16;

    bf16x8 qfA[2], qfB[2];
    #pragma unroll
    for (int c = 0; c < 2; ++c) {
        qfA[c] = *(const bf16x8*)(qp + (size_t)(q0A + lr) * 3072 + c * 32 + lc * 8);
        qfB[c] = *(const bf16x8*)(qp + (size_t)(q0B + lr) * 3072 + c * 32 + lc * 8);
    }

    f32x4 accA[4] = {}, accB[4] = {};
    float mA[4], lA_[4], mB[4], lB_[4];
    #pragma unroll
    for (int r = 0; r < 4; ++r) { mA[r] = -INFINITY; lA_[r] = 0.f; mB[r] = -INFINITY; lB_[r] = 0.f; }

    // online-softmax update for one 64-row tile held as s[4] frags
    auto smax = [&](f32x4* s, f32x4* acc, float* m, float* lsum, int kv0, int q0, bool bnd) {
        #pragma unroll
        for (int r = 0; r < 4; ++r) {
            float mr = -1e30f;
            #pragma unroll
            for (int j = 0; j < 4; ++j) {
                float v = s[j][r] * 0.125f;
                if (bnd && (kv0 + j * 16 + lr) > (q0 + lc * 4 + r)) v = -1e30f;
                s[j][r] = v;
                mr = fmaxf(mr, v);
            }
            #pragma unroll
            for (int d = 1; d < 16; d <<= 1) mr = fmaxf(mr, __shfl_xor(mr, d));
            float mnew = fmaxf(m[r], mr);
            float fct  = __expf(m[r] - mnew);
            float ps = 0.f;
            #pragma unroll
            for (int j = 0; j < 4; ++j) {
                float p = __expf(s[j][r] - mnew);
                s[j][r] = p;
                ps += p;
            }
            #pragma unroll
            for (int d = 1; d < 16; d <<= 1) ps += __shfl_xor(ps, d);
            lsum[r] = lsum[r] * fct + ps;
            m[r] = mnew;
            #pragma unroll
            for (int f = 0; f < 4; ++f) acc[f][r] *= fct;
        }
    };

    for (int kt = 0; kt <= qtB; ++kt) {
        const int kv0 = kt * 64;
        const bool doA = (kt <= qtA);

        // QK^T for both tiles, sharing K fragment loads
        f32x4 sA[4] = {}, sB[4] = {};
        #pragma unroll
        for (int j = 0; j < 4; ++j)
            #pragma unroll
            for (int c = 0; c < 2; ++c) {
                bf16x8 kf = *(const bf16x8*)(kp + (size_t)(kv0 + j * 16 + lr) * 3072 + c * 32 + lc * 8);
                if (doA) sA[j] = __builtin_amdgcn_mfma_f32_16x16x32_bf16(qfA[c], kf, sA[j], 0, 0, 0);
                sB[j] = __builtin_amdgcn_mfma_f32_16x16x32_bf16(qfB[c], kf, sB[j], 0, 0, 0);
            }

        if (doA) smax(sA, accA, mA, lA_, kv0, q0A, kt == qtA);
        smax(sB, accB, mB, lB_, kv0, q0B, kt == qtB);

        // P -> wave-private LDS (transpose to A-operand layout)
        if (doA)
            #pragma unroll
            for (int r = 0; r < 4; ++r)
                #pragma unroll
                for (int j = 0; j < 4; ++j)
                    Pl[w][0][(lc * 4 + r) * 72 + j * 16 + lr] = f2bf(sA[j][r]);
        #pragma unroll
        for (int r = 0; r < 4; ++r)
            #pragma unroll
            for (int j = 0; j < 4; ++j)
                Pl[w][1][(lc * 4 + r) * 72 + j * 16 + lr] = f2bf(sB[j][r]);

        bf16x8 paA[2], paB[2];
        #pragma unroll
        for (int c = 0; c < 2; ++c) {
            paA[c] = *(const bf16x8*)&Pl[w][0][lr * 72 + c * 32 + lc * 8];
            paB[c] = *(const bf16x8*)&Pl[w][1][lr * 72 + c * 32 + lc * 8];
        }

        // PV, sharing V^T fragment loads (rows of vt, 16B aligned, L2-hot)
        #pragma unroll
        for (int f = 0; f < 4; ++f)
            #pragma unroll
            for (int c = 0; c < 2; ++c) {
                bf16x8 vf = *(const bf16x8*)(vb + (size_t)(f * 16 + lr) * SEQ + kv0 + c * 32 + lc * 8);
                if (doA) accA[f] = __builtin_amdgcn_mfma_f32_16x16x32_bf16(paA[c], vf, accA[f], 0, 0, 0);
                accB[f] = __builtin_amdgcn_mfma_f32_16x16x32_bf16(paB[c], vf, accB[f], 0, 0, 0);
            }
    }

    unsigned short* op = out + (size_t)(b * SEQ) * DIMM + h * 64;
    #pragma unroll
    for (int r = 0; r < 4; ++r) {
        float invA = 1.0f / lA_[r];
        float invB = 1.0f / lB_[r];
        #pragma unroll
        for (int f = 0; f < 4; ++f) {
            op[(size_t)(q0A + lc * 4 + r) * DIMM + f * 16 + lr] = f2bf(accA[f][r] * invA);
            op[(size_t)(q0B + lc * 4 + r) * DIMM + f * 16 + lr] = f2bf(accB[f][r] * invB);
        }
    }
}

// ---------------------------------------------------------------------------
extern "C" void kernel_launch(void* const* d_in, const int* in_sizes, int n_in,
                              void* d_out, int out_size, void* d_ws, size_t ws_size,
                              hipStream_t stream) {
    const float* x     = (const float*)d_in[0];   // [4,2048,1024]
    const float* w_qkv = (const float*)d_in[1];   // [1024,3072]
    const float* w_out = (const float*)d_in[2];   // [1024,1024]

    unsigned short* x_bf   = (unsigned short*)d_ws;                  // 8192*1024
    unsigned short* wqkvT  = x_bf   + (size_t)MROWS * DIMM;          // 3072*1024
    unsigned short* woutT  = wqkvT  + (size_t)3 * DIMM * DIMM;       // 1024*1024
    unsigned short* qkv_bf = woutT  + (size_t)DIMM * DIMM;           // 8192*3072
    unsigned short* aout   = qkv_bf + (size_t)MROWS * 3 * DIMM;      // 8192*1024
    unsigned short* vt     = x_bf;   // x_bf is dead after the QKV GEMM; alias it

    // 1. converts / transposes
    k_conv_bf16<<<(MROWS * DIMM / 4 + 255) / 256, 256, 0, stream>>>(x, x_bf, MROWS * DIMM / 4);
    dim3 g1(3 * DIMM / 32, DIMM / 32);
    k_transpose<<<g1, 256, 0, stream>>>(w_qkv, wqkvT, DIMM, 3 * DIMM);
    dim3 g2(DIMM / 32, DIMM / 32);
    k_transpose<<<g2, 256, 0, stream>>>(w_out, woutT, DIMM, DIMM);

    // 2. QKV projection: [8192,1024] x [1024,3072] -> bf16 [8192,3072]
    k_gemm_bt<1><<<(MROWS / 128) * (3 * DIMM / 128), 256, 0, stream>>>(
        x_bf, wqkvT, qkv_bf, MROWS, 3 * DIMM, DIMM);

    // 3. per-head V^T (overwrites x_bf region)
    k_transpose_v<<<64 * 32, 256, 0, stream>>>(qkv_bf, vt);

    // 4. causal flash attention -> bf16 [8192,1024]
    k_attn2<<<NB * NH * 16, 256, 0, stream>>>(qkv_bf, vt, aout);

    // 5. output projection: [8192,1024] x [1024,1024] -> fp32 d_out
    k_gemm_bt<0><<<(MROWS / 128) * (DIMM / 128), 256, 0, stream>>>(
        aout, woutT, d_out, MROWS, DIMM, DIMM);
}

// Round 5
// 314.326 us; speedup vs baseline: 1.4365x; 1.2724x over previous
//
#include <hip/hip_runtime.h>
#include <hip/hip_bf16.h>
#include <stdint.h>

// Problem constants
#define SEQ  2048
#define DIMM 1024
#define NH   16
#define DH   64
#define NB   4
#define MROWS (NB*SEQ)   // 8192

typedef __attribute__((ext_vector_type(8))) short bf16x8;
typedef __attribute__((ext_vector_type(4))) float f32x4;
typedef __attribute__((ext_vector_type(16))) float f32x16;

__device__ __forceinline__ unsigned short f2bf(float f) {
    union { float f; uint32_t u; } c; c.f = f;
    uint32_t r = c.u + 0x7fff + ((c.u >> 16) & 1);
    return (unsigned short)(r >> 16);
}

__device__ __forceinline__ void gload_lds16(const void* g, void* lds) {
    __builtin_amdgcn_global_load_lds(
        (const __attribute__((address_space(1))) unsigned int*)(g),
        (__attribute__((address_space(3))) unsigned int*)(lds),
        16, 0, 0);
}

// ---------------- fp32 -> bf16 elementwise convert (vectorized) -------------
__global__ __launch_bounds__(256) void k_conv_bf16(const float* __restrict__ in,
                                                   unsigned short* __restrict__ out,
                                                   int n4) {
    int i = blockIdx.x * 256 + threadIdx.x;
    if (i >= n4) return;
    float4 v = ((const float4*)in)[i];
    ushort4 o;
    o.x = f2bf(v.x); o.y = f2bf(v.y); o.z = f2bf(v.z); o.w = f2bf(v.w);
    ((ushort4*)out)[i] = o;
}

// ------------- W [K][N] fp32  ->  Wt [N][K] bf16 (tiled transpose) ----------
__global__ __launch_bounds__(256) void k_transpose(const float* __restrict__ W,
                                                   unsigned short* __restrict__ Wt,
                                                   int K, int N) {
    __shared__ unsigned short tile[32][33];
    int tn = blockIdx.x, tk = blockIdx.y;
    int lx = threadIdx.x & 31, ly = threadIdx.x >> 5;  // 32 x 8
    #pragma unroll
    for (int i = 0; i < 32; i += 8) {
        int k = tk * 32 + ly + i;
        int n = tn * 32 + lx;
        tile[ly + i][lx] = f2bf(W[(size_t)k * N + n]);
    }
    __syncthreads();
    int k2 = tk * 32 + lx;
    #pragma unroll
    for (int i = 0; i < 32; i += 8) {
        int n2 = tn * 32 + ly + i;
        Wt[(size_t)n2 * K + k2] = tile[lx][ly + i];
    }
}

// ---- V columns of qkv  ->  vt[bh][d=64][n=2048] bf16 (per-head V^T) --------
__global__ __launch_bounds__(256) void k_transpose_v(const unsigned short* __restrict__ qkv,
                                                     unsigned short* __restrict__ vt) {
    __shared__ unsigned short tile[64 * 72];
    const int nt = blockIdx.x & 31;      // kv tile of 64
    const int bh = blockIdx.x >> 5;      // 0..63
    const int b = bh >> 4, h = bh & 15;
    const int n0 = nt * 64;
    const int t = threadIdx.x;

    #pragma unroll
    for (int i = 0; i < 2; ++i) {
        int c = t + 256 * i;
        int kv = c >> 3, d0 = (c & 7) * 8;
        bf16x8 v = *(const bf16x8*)(qkv + (size_t)(b * SEQ + n0 + kv) * 3072 + 2048 + h * 64 + d0);
        *(bf16x8*)&tile[kv * 72 + d0] = v;
    }
    __syncthreads();
    #pragma unroll
    for (int i = 0; i < 2; ++i) {
        int c = t + 256 * i;
        int d = c >> 3, k0 = (c & 7) * 8;
        bf16x8 o;
        #pragma unroll
        for (int e = 0; e < 8; ++e)
            ((unsigned short*)&o)[e] = tile[(k0 + e) * 72 + d];
        *(bf16x8*)(vt + (size_t)(bh * 64 + d) * SEQ + n0 + k0) = o;
    }
}

// --------- C[M][N] = A[M][K] * Bt[N][K]^T   (bf16 in, fp32/bf16 out) --------
template<int OUT_BF16>
__global__ __launch_bounds__(256) void k_gemm_bt(const unsigned short* __restrict__ A,
                                                 const unsigned short* __restrict__ Bt,
                                                 void* __restrict__ Cv,
                                                 int M, int N_, int K) {
    constexpr int BM = 128, BN = 128, BK = 32;
    __shared__ unsigned short lA[BM * BK];
    __shared__ unsigned short lB[BN * BK];
    const int ntile = N_ / BN;
    const int tm = blockIdx.x / ntile;
    const int tn = blockIdx.x % ntile;
    const int t = threadIdx.x;
    const int w = t >> 6, l = t & 63;
    const int wr = w >> 1, wc = w & 1;

    const unsigned short* Abase = A + (size_t)tm * BM * K;
    const unsigned short* Bbase = Bt + (size_t)tn * BN * K;

    f32x4 acc[4][4] = {};

    for (int k0 = 0; k0 < K; k0 += BK) {
        __syncthreads();
        #pragma unroll
        for (int i = 0; i < 2; ++i) {
            int offL = (i * 4 + w) * 1024 + l * 16;
            int row = offL >> 6;
            int kb  = offL & 63;
            gload_lds16((const char*)(Abase + (size_t)row * K + k0) + kb,
                        (char*)lA + (i * 4 + w) * 1024);
            gload_lds16((const char*)(Bbase + (size_t)row * K + k0) + kb,
                        (char*)lB + (i * 4 + w) * 1024);
        }
        __syncthreads();

        bf16x8 af[4], bfv[4];
        #pragma unroll
        for (int i = 0; i < 4; ++i)
            af[i] = *(const bf16x8*)&lA[(wr * 64 + i * 16 + (l & 15)) * BK + (l >> 4) * 8];
        #pragma unroll
        for (int j = 0; j < 4; ++j)
            bfv[j] = *(const bf16x8*)&lB[(wc * 64 + j * 16 + (l & 15)) * BK + (l >> 4) * 8];
        #pragma unroll
        for (int i = 0; i < 4; ++i)
            #pragma unroll
            for (int j = 0; j < 4; ++j)
                acc[i][j] = __builtin_amdgcn_mfma_f32_16x16x32_bf16(af[i], bfv[j], acc[i][j], 0, 0, 0);
    }

    float* Cf = (float*)Cv;
    unsigned short* Cb = (unsigned short*)Cv;
    const int row0 = tm * BM + wr * 64 + (l >> 4) * 4;
    const int col0 = tn * BN + wc * 64 + (l & 15);
    #pragma unroll
    for (int i = 0; i < 4; ++i)
        #pragma unroll
        for (int j = 0; j < 4; ++j)
            #pragma unroll
            for (int r = 0; r < 4; ++r) {
                size_t idx = (size_t)(row0 + i * 16 + r) * N_ + (col0 + j * 16);
                if (OUT_BF16) Cb[idx] = f2bf(acc[i][j][r]);
                else          Cf[idx] = acc[i][j][r];
            }
}

// ------------- causal flash attention (v5: swapped QK^T + LDS-P) ------------
// mfma(K,Q) => lane holds P[q=l&31][kv=crow(r,hi)], softmax lane-local.
// accO rows are crow-indexed => rescale needs the ROW's factor: shfl(fct,crow).
// P -> PV A-operand via wave-private padded LDS round-trip. No barriers.
__global__ __launch_bounds__(256, 2) void k_attn5(const unsigned short* __restrict__ qkv,
                                                  const unsigned short* __restrict__ vt,
                                                  unsigned short* __restrict__ out) {
    // bijective XCD swizzle (1024 = 8*128)
    const int wid = (blockIdx.x & 7) * 128 + (blockIdx.x >> 3);
    const int bh = wid >> 4;                  // 0..63
    const int chunk = 15 - (wid & 15);        // 0..15
    const int b = bh >> 4, h = bh & 15;
    const int w = threadIdx.x >> 6, l = threadIdx.x & 63;
    const int l31 = l & 31, hi = l >> 5;

    // wave-private P buffer: [32 q][64 kv] bf16, row stride 34 u32 words
    __shared__ unsigned int Pbuf[4][32 * 34];
    unsigned int* Pw = Pbuf[w];

    const unsigned short* qp = qkv + (size_t)(b * SEQ) * 3072 + h * 64;
    const unsigned short* kp = qp + 1024;
    const unsigned short* vb = vt + (size_t)bh * 64 * SEQ;

    const int q0w = chunk * 128 + w * 32;     // wave's first q row
    const int qrow = q0w + l31;               // this lane's q row
    const int nt = (q0w >> 6) + 1;            // kv-tile trip count (last masked)

    // Q as B-operand: col = l31 (q), k = m*16 + hi*8 + e
    bf16x8 qf[4];
    #pragma unroll
    for (int m = 0; m < 4; ++m)
        qf[m] = *(const bf16x8*)(qp + (size_t)(q0w + l31) * 3072 + m * 16 + hi * 8);

    f32x16 accO0 = {}, accO1 = {};
    float m_run = -INFINITY, l_run = 0.f;

    // K as A-operand: row kv = f*32 + l31, k = m*16 + hi*8 + e
    bf16x8 kf[2][4];
    #pragma unroll
    for (int f = 0; f < 2; ++f)
        #pragma unroll
        for (int m = 0; m < 4; ++m)
            kf[f][m] = *(const bf16x8*)(kp + (size_t)(f * 32 + l31) * 3072 + m * 16 + hi * 8);

    union PU { uint2 d2[2]; bf16x8 v; };

    for (int kt = 0; kt < nt; ++kt) {
        const int kv0 = kt * 64;
        const bool msk = (kt == nt - 1);

        // QK^T swapped -> S^T: lane holds q=l31, kv = f*32 + crow(r,hi)
        f32x16 s0 = {}, s1 = {};
        __builtin_amdgcn_s_setprio(1);
        #pragma unroll
        for (int m = 0; m < 4; ++m) {
            s0 = __builtin_amdgcn_mfma_f32_32x32x16_bf16(kf[0][m], qf[m], s0, 0, 0, 0);
            s1 = __builtin_amdgcn_mfma_f32_32x32x16_bf16(kf[1][m], qf[m], s1, 0, 0, 0);
        }
        __builtin_amdgcn_s_setprio(0);

        // V loads issued early (latency hides under softmax)
        bf16x8 vf0[4], vf1[4];
        #pragma unroll
        for (int m = 0; m < 4; ++m) {
            vf0[m] = *(const bf16x8*)(vb + (size_t)l31 * SEQ + kv0 + m * 16 + hi * 8);
            vf1[m] = *(const bf16x8*)(vb + (size_t)(32 + l31) * SEQ + kv0 + m * 16 + hi * 8);
        }
        // K prefetch for next tile (kf dead after QK^T above)
        const int kvn = (kt + 1 < nt) ? kv0 + 64 : kv0;
        #pragma unroll
        for (int f = 0; f < 2; ++f)
            #pragma unroll
            for (int m = 0; m < 4; ++m)
                kf[f][m] = *(const bf16x8*)(kp + (size_t)(kvn + f * 32 + l31) * 3072 + m * 16 + hi * 8);

        // ---- in-lane online softmax (lane owns q row = l31) ----
        float tmax = -1e30f;
        #pragma unroll
        for (int r = 0; r < 16; ++r) {
            const int crow = (r & 3) + 8 * (r >> 2) + 4 * hi;
            float v0 = s0[r] * 0.125f;
            float v1 = s1[r] * 0.125f;
            if (msk) {
                if (kv0 + crow > qrow)      v0 = -1e30f;
                if (kv0 + 32 + crow > qrow) v1 = -1e30f;
            }
            s0[r] = v0; s1[r] = v1;
            tmax = fmaxf(tmax, fmaxf(v0, v1));
        }
        tmax = fmaxf(tmax, __shfl_xor(tmax, 32));      // other kv half
        const float mnew = fmaxf(m_run, tmax);
        const float fct = __expf(m_run - mnew);
        float ps = 0.f;
        #pragma unroll
        for (int r = 0; r < 16; ++r) {
            float p0 = __expf(s0[r] - mnew);
            float p1 = __expf(s1[r] - mnew);
            s0[r] = p0; s1[r] = p1;
            ps += p0 + p1;
        }
        ps += __shfl_xor(ps, 32);
        l_run = l_run * fct + ps;
        m_run = mnew;

        // ---- P -> wave-private LDS (q-row l31, packed kv pairs) ----
        // s0[4g+j] -> kv = 8g + 4hi + j  (consecutive per g)
        #pragma unroll
        for (int g = 0; g < 4; ++g) {
            uint2 w0, w1;
            w0.x = (unsigned int)f2bf(s0[4 * g + 0]) | ((unsigned int)f2bf(s0[4 * g + 1]) << 16);
            w0.y = (unsigned int)f2bf(s0[4 * g + 2]) | ((unsigned int)f2bf(s0[4 * g + 3]) << 16);
            w1.x = (unsigned int)f2bf(s1[4 * g + 0]) | ((unsigned int)f2bf(s1[4 * g + 1]) << 16);
            w1.y = (unsigned int)f2bf(s1[4 * g + 2]) | ((unsigned int)f2bf(s1[4 * g + 3]) << 16);
            *(uint2*)&Pw[l31 * 34 + 4 * g + 2 * hi]      = w0;   // kv 0..31 half
            *(uint2*)&Pw[l31 * 34 + 16 + 4 * g + 2 * hi] = w1;   // kv 32..63 half
        }

        // ---- rescale O with the ROW-matched factor (row = crow, not l31!) ----
        #pragma unroll
        for (int r = 0; r < 16; ++r) {
            const int crow = (r & 3) + 8 * (r >> 2) + 4 * hi;
            const float fr = __shfl(fct, crow);   // lane crow holds row crow's factor
            accO0[r] *= fr;
            accO1[r] *= fr;
        }

        // ---- read back PV A-fragments: P[q=l31][kv = m*16 + hi*8 + 0..7] ----
        bf16x8 pa[4];
        #pragma unroll
        for (int m = 0; m < 4; ++m) {
            PU pu;
            pu.d2[0] = *(const uint2*)&Pw[l31 * 34 + m * 8 + 4 * hi];
            pu.d2[1] = *(const uint2*)&Pw[l31 * 34 + m * 8 + 4 * hi + 2];
            pa[m] = pu.v;
        }

        __builtin_amdgcn_s_setprio(1);
        #pragma unroll
        for (int m = 0; m < 4; ++m) {
            accO0 = __builtin_amdgcn_mfma_f32_32x32x16_bf16(pa[m], vf0[m], accO0, 0, 0, 0);
            accO1 = __builtin_amdgcn_mfma_f32_32x32x16_bf16(pa[m], vf1[m], accO1, 0, 0, 0);
        }
        __builtin_amdgcn_s_setprio(0);
    }

    // epilogue: O[q][d], row q = q0w + crow(r,hi), col d = 32n + l31
    unsigned short* op = out + (size_t)(b * SEQ) * DIMM + h * 64;
    #pragma unroll
    for (int r = 0; r < 16; ++r) {
        const int crow = (r & 3) + 8 * (r >> 2) + 4 * hi;
        float inv = 1.0f / __shfl(l_run, crow);   // lane crow holds that row's sum
        const size_t rowoff = (size_t)(q0w + crow) * DIMM;
        op[rowoff + l31]      = f2bf(accO0[r] * inv);
        op[rowoff + 32 + l31] = f2bf(accO1[r] * inv);
    }
}

// ---------------------------------------------------------------------------
extern "C" void kernel_launch(void* const* d_in, const int* in_sizes, int n_in,
                              void* d_out, int out_size, void* d_ws, size_t ws_size,
                              hipStream_t stream) {
    const float* x     = (const float*)d_in[0];   // [4,2048,1024]
    const float* w_qkv = (const float*)d_in[1];   // [1024,3072]
    const float* w_out = (const float*)d_in[2];   // [1024,1024]

    unsigned short* x_bf   = (unsigned short*)d_ws;                  // 8192*1024
    unsigned short* wqkvT  = x_bf   + (size_t)MROWS * DIMM;          // 3072*1024
    unsigned short* woutT  = wqkvT  + (size_t)3 * DIMM * DIMM;       // 1024*1024
    unsigned short* qkv_bf = woutT  + (size_t)DIMM * DIMM;           // 8192*3072
    unsigned short* aout   = qkv_bf + (size_t)MROWS * 3 * DIMM;      // 8192*1024
    unsigned short* vt     = x_bf;   // x_bf dead after QKV GEMM; alias it

    // 1. converts / transposes
    k_conv_bf16<<<(MROWS * DIMM / 4 + 255) / 256, 256, 0, stream>>>(x, x_bf, MROWS * DIMM / 4);
    dim3 g1(3 * DIMM / 32, DIMM / 32);
    k_transpose<<<g1, 256, 0, stream>>>(w_qkv, wqkvT, DIMM, 3 * DIMM);
    dim3 g2(DIMM / 32, DIMM / 32);
    k_transpose<<<g2, 256, 0, stream>>>(w_out, woutT, DIMM, DIMM);

    // 2. QKV projection: [8192,1024] x [1024,3072] -> bf16 [8192,3072]
    k_gemm_bt<1><<<(MROWS / 128) * (3 * DIMM / 128), 256, 0, stream>>>(
        x_bf, wqkvT, qkv_bf, MROWS, 3 * DIMM, DIMM);

    // 3. per-head V^T (overwrites x_bf region)
    k_transpose_v<<<64 * 32, 256, 0, stream>>>(qkv_bf, vt);

    // 4. causal flash attention -> bf16 [8192,1024]
    k_attn5<<<NB * NH * 16, 256, 0, stream>>>(qkv_bf, vt, aout);

    // 5. output projection: [8192,1024] x [1024,1024] -> fp32 d_out
    k_gemm_bt<0><<<(MROWS / 128) * (DIMM / 128), 256, 0, stream>>>(
        aout, woutT, d_out, MROWS, DIMM, DIMM);
}